// Round 13
// baseline (121.499 us; speedup 1.0000x reference)
//
#include <hip/hip_runtime.h>

// ============================================================================
// AttentionWithSpatial: x@Wqkv -> masked/biased 4-head attention -> @Wout+b
// b=4, n=2048, dim=256, heads=4, dhead=64, scale=0.125
//
// R12 post-mortem: barrier-free k_attn quadrupled K/V L2 traffic (each wave
// streams its own copy) -> L2-BW bound ~54us; k_prep 55us at 2x its traffic
// floor (ILP-starved scattered reads). R13:
//  - k_attn: K/V shared via LDS dbuf (1x L2 traffic) + RAW s_barrier with
//    lgkmcnt(0) only (NO vmcnt drain -- prefetch stays in flight across the
//    barrier, AITER pattern). Swapped PV / lane-local softmax / bias
//    acc-init kept from R12. One barrier per iter.
//  - k_prep: 2 adjacent-kt bias records per thread (8 loads in flight,
//    256B/row contiguous per wave).
//  - k_qkv/k_comb/k_out + aliasing identical to passing R12.
// ============================================================================

#define B_   4
#define N_   2048
#define H_   4
#define DH_  64
#define DIMX 256
#define M_   (B_*N_)   // 8192

#define LOG2E  1.4426950408889634f
#define NEGINF (-1e30f)
#define DEFER_THR 8.0f

typedef __attribute__((ext_vector_type(8))) short short8;
typedef __attribute__((ext_vector_type(4))) float f32x4;
typedef unsigned short u16;
typedef unsigned int   u32;

#define MFMA16(a,b,c) __builtin_amdgcn_mfma_f32_16x16x32_bf16((a),(b),(c),0,0,0)

__device__ __forceinline__ u16 f2bf(float f) {
  u32 u = __builtin_bit_cast(u32, f);
  u += 0x7fffu + ((u >> 16) & 1u);   // RNE
  return (u16)(u >> 16);
}
__device__ __forceinline__ float bf2f(u16 h) {
  u32 u = ((u32)h) << 16;
  return __builtin_bit_cast(float, u);
}
__device__ __forceinline__ void split2(float f, u16* hi, u16* lo) {
  u16 h = f2bf(f);
  *hi = h;
  *lo = f2bf(f - bf2f(h));
}
__device__ __forceinline__ u32 cvtpk(float lo, float hi) {
  u32 r;
  asm("v_cvt_pk_bf16_f32 %0, %1, %2" : "=v"(r) : "v"(lo), "v"(hi));
  return r;
}

struct u16v4 { u16 a, b, c, d; };
struct u16v8 { u16 v[8]; };

// ---------------------------------------------------------------------------
// Kernel 1 (fused prep):
//  blocks [0,4096): bias prefuse, TWO adjacent-kt records per thread
//  blocks [4096,7168): x -> xh/xl split; Wqkv/Wout transpose+split
// ---------------------------------------------------------------------------
__global__ __launch_bounds__(256) void k_prep(
    const int* __restrict__ mask, const float* __restrict__ spat,
    const float* __restrict__ x, const float* __restrict__ wq,
    const float* __restrict__ wo,
    u16* __restrict__ biasF,
    u16* __restrict__ xh, u16* __restrict__ xl,
    u16* __restrict__ wqh, u16* __restrict__ wql,
    u16* __restrict__ woh, u16* __restrict__ wol)
{
  if (blockIdx.x < 4096) {
    const int rr = blockIdx.x * 256 + threadIdx.x;    // [0, 1048576)
    const int lane = rr & 63;
    const int kt2 = (rr >> 6) & 31;                   // kt pair
    const int qt = (rr >> 11) & 127;
    const int b  = rr >> 18;
    const int kt = kt2 * 2;
    const int ln = lane & 15, hb = lane >> 4;
    const int q  = qt * 16 + ln;
    const int c0 = kt * 32 + hb * 4;
    const int base = (b * N_ + q) * N_ + c0;

    int4   m[4];
    float4 s[4];
#pragma unroll
    for (int i = 0; i < 4; ++i) {
      m[i] = *(const int4*)&mask[base + i * 16];
      s[i] = *(const float4*)&spat[base + i * 16];
    }

    const float NB = -10000.0f;
    const size_t r0 = ((size_t)((b * 128 + qt) * 64 + kt) * 64 + lane) * 8;
#pragma unroll
    for (int g = 0; g < 2; ++g) {      // record kt+g
      u16v8 o;
      const int4   ma = m[g * 2], mb = m[g * 2 + 1];
      const float4 sa = s[g * 2], sb = s[g * 2 + 1];
      o.v[0] = __builtin_bit_cast(u16, (_Float16)(ma.x ? sa.x * LOG2E : NB));
      o.v[1] = __builtin_bit_cast(u16, (_Float16)(ma.y ? sa.y * LOG2E : NB));
      o.v[2] = __builtin_bit_cast(u16, (_Float16)(ma.z ? sa.z * LOG2E : NB));
      o.v[3] = __builtin_bit_cast(u16, (_Float16)(ma.w ? sa.w * LOG2E : NB));
      o.v[4] = __builtin_bit_cast(u16, (_Float16)(mb.x ? sb.x * LOG2E : NB));
      o.v[5] = __builtin_bit_cast(u16, (_Float16)(mb.y ? sb.y * LOG2E : NB));
      o.v[6] = __builtin_bit_cast(u16, (_Float16)(mb.z ? sb.z * LOG2E : NB));
      o.v[7] = __builtin_bit_cast(u16, (_Float16)(mb.w ? sb.w * LOG2E : NB));
      *(u16v8*)&biasF[r0 + (size_t)g * 512] = o;
    }
    return;
  }

  const int NX4 = (M_ * DIMX) / 4;  // 524288
  const int NWQ = 768 * 256;        // 196608
  const int NWO = 256 * 256;        // 65536
  int i = (blockIdx.x - 4096) * 256 + threadIdx.x;
  if (i < NX4) {
    const float4 v = ((const float4*)x)[i];
    u16v4 hv, lv;
    split2(v.x, &hv.a, &lv.a);
    split2(v.y, &hv.b, &lv.b);
    split2(v.z, &hv.c, &lv.c);
    split2(v.w, &hv.d, &lv.d);
    ((u16v4*)xh)[i] = hv;
    ((u16v4*)xl)[i] = lv;
  } else if (i < NX4 + NWQ) {
    int j = i - NX4;
    int c = j >> 8, k = j & 255;            // out layout [c][k]
    split2(wq[k * 768 + c], &wqh[j], &wql[j]);
  } else if (i < NX4 + NWQ + NWO) {
    int j = i - NX4 - NWQ;
    int c = j >> 8, k = j & 255;
    split2(wo[k * 256 + c], &woh[j], &wol[j]);
  }
}

// ---------------------------------------------------------------------------
// Kernel 2: QKV GEMM, LDS-staged. M=8192, N=768, K=256. grid (12, 64).
// B tile (hi+lo) staged once in 64KB LDS, XOR-swizzled; 2 M-subtiles/block;
// 16 A loads upfront per subtile; MFMA fed from LDS.
// ---------------------------------------------------------------------------
__global__ __launch_bounds__(256) void k_qkv(
    const u16* __restrict__ xh, const u16* __restrict__ xl,
    const u16* __restrict__ wh, const u16* __restrict__ wl,
    u16* __restrict__ qh, u16* __restrict__ ql,
    u16* __restrict__ kf, u16* __restrict__ vf)
{
  __shared__ __align__(16) u16 BhL[64 * 256];   // 32 KB, swizzled
  __shared__ __align__(16) u16 BlL[64 * 256];   // 32 KB

  const int tid = threadIdx.x;
  const int w = tid >> 6, lane = tid & 63;
  const int ln = lane & 15, hb = lane >> 4;
  const int colb = blockIdx.x * 64;

  // ---- stage B (hi+lo) into LDS, reg-batched, coalesced ----
  {
    short8 sb[16];
#pragma unroll
    for (int it = 0; it < 8; ++it) {
      const int c = it * 8 + (tid >> 5), k8 = tid & 31;
      sb[it]     = *(const short8*)&wh[(colb + c) * 256 + k8 * 8];
      sb[8 + it] = *(const short8*)&wl[(colb + c) * 256 + k8 * 8];
    }
#pragma unroll
    for (int it = 0; it < 8; ++it) {
      const int c = it * 8 + (tid >> 5), k8 = tid & 31;
      const int le = c * 256 + ((k8 * 8) ^ ((c & 7) << 3));
      *(short8*)&BhL[le] = sb[it];
      *(short8*)&BlL[le] = sb[8 + it];
    }
  }
  __syncthreads();

#pragma unroll
  for (int st = 0; st < 2; ++st) {
    const int mtile = blockIdx.y * 2 + st;
    const int arow = mtile * 64 + w * 16 + ln;

    short8 a_h8[8], a_l8[8];
#pragma unroll
    for (int ks = 0; ks < 8; ++ks) {
      a_h8[ks] = *(const short8*)&xh[arow * 256 + ks * 32 + hb * 8];
      a_l8[ks] = *(const short8*)&xl[arow * 256 + ks * 32 + hb * 8];
    }

    f32x4 acc[4] = {};
#pragma unroll
    for (int ks = 0; ks < 8; ++ks) {
      const int k0 = ks * 32 + hb * 8;
#pragma unroll
      for (int j = 0; j < 4; ++j) {
        const int c = j * 16 + ln;
        const int le = c * 256 + (k0 ^ ((c & 7) << 3));
        const short8 b_h = *(const short8*)&BhL[le];
        const short8 b_l = *(const short8*)&BlL[le];
        acc[j] = MFMA16(a_h8[ks], b_h, acc[j]);
        acc[j] = MFMA16(a_l8[ks], b_h, acc[j]);
        acc[j] = MFMA16(a_h8[ks], b_l, acc[j]);
      }
    }

    const int mbase = mtile * 64 + w * 16 + hb * 4;
#pragma unroll
    for (int j = 0; j < 4; ++j) {
      const int c = colb + j * 16 + ln;
      const int which = c >> 8;        // 0=q 1=k 2=v
      const int hd = c & 255;
      const int hh = hd >> 6, d = hd & 63;
#pragma unroll
      for (int r = 0; r < 4; ++r) {
        const int m = mbase + r;
        const int bb = m >> 11, nn = m & 2047;
        const int bh = bb * H_ + hh;
        float v = acc[j][r];
        if (which == 0) {
          const int off = (bh * N_ + nn) * DH_ + d;
          v *= (0.125f * LOG2E);                 // scale + exp2-domain fold
          split2(v, &qh[off], &ql[off]);
        } else if (which == 1) {
          const int ktile = nn >> 5, jj = (nn >> 4) & 1, lnn = nn & 15;
          const int kc = d >> 5, hbb = (d >> 3) & 3, e = d & 7;
          const int off = (bh * 64 + ktile) * 2048 + (kc * 2 + jj) * 512
                        + (hbb * 16 + lnn) * 8 + e;
          kf[off] = f2bf(v);
        } else {
          const int ktile = nn >> 5, hbb = (nn >> 3) & 3, e = nn & 7;
          const int j2 = d >> 4, lnn = d & 15;
          const int off = (bh * 64 + ktile) * 2048 + j2 * 512
                        + (hbb * 16 + lnn) * 8 + e;
          vf[off] = f2bf(v);
        }
      }
    }
  }
}

// ---------------------------------------------------------------------------
// Kernel 3: flash attention partials, KV-split=2. grid 1024:
// bid = qq*32 + bh*2 + half; 4 waves = 4 q-tiles of SAME head share K/V in
// LDS (dbuf). Staging: global->reg early, ds_write late; sync via RAW
// s_barrier preceded by lgkmcnt(0) ONLY (no vmcnt drain -- next-tile global
// prefetch stays in flight across the barrier). Swapped PV (O=[d][q], q=ln
// lane-local rescale/l), bias fp16 acc-init, defer-max. One barrier/iter.
// ---------------------------------------------------------------------------
__global__ __launch_bounds__(256) void k_attn(
    const u16* __restrict__ qhg, const u16* __restrict__ qlg,
    const u16* __restrict__ kfg, const u16* __restrict__ vfg,
    const u16* __restrict__ biasF,
    float* __restrict__ Op0, float* __restrict__ Op1,
    float* __restrict__ MP, float* __restrict__ LP)
{
  __shared__ __align__(16) u16 KL[2][2048];    // 8 KB  (32x64 bf16 tile)
  __shared__ __align__(16) u16 VL[2][2048];    // 8 KB  (V^T fragments)
  __shared__ __align__(16) u32 Pbuf[4][320];   // 5 KB, per-wave P exchange

  const int bid = blockIdx.x;
  const int half = bid & 1;
  const int bh = (bid >> 1) & 15;
  const int qq = bid >> 5;
  const int b = bh >> 2, h = bh & 3;
  const int kt0 = half * 32;

  const int tid = threadIdx.x;
  const int w = tid >> 6, lane = tid & 63;
  const int qt = qq * 4 + w;                   // this wave's q-tile [0,128)
  const int ln = lane & 15, hb = lane >> 4;

  // ---- Q fragments (pre-scaled by 0.125*log2e), hi/lo ----
  short8 qfh[2], qfl[2];
  {
    const int base = ((b * H_ + h) * N_ + qt * 16 + ln) * DH_;
    qfh[0] = *(const short8*)&qhg[base + hb * 8];
    qfh[1] = *(const short8*)&qhg[base + 32 + hb * 8];
    qfl[0] = *(const short8*)&qlg[base + hb * 8];
    qfl[1] = *(const short8*)&qlg[base + 32 + hb * 8];
  }

  const u16* Kt0 = kfg + (size_t)((b * H_ + h) * 64) * 2048;
  const u16* Vt0 = vfg + (size_t)((b * H_ + h) * 64) * 2048;
  const u16* Bt0 = biasF + (size_t)((b * 128 + qt) * 64) * 512 + lane * 8;
  const int stoff = tid * 8;             // staging slot: 16B per thread
  const int l8 = lane * 8;

  short8 ones;
#pragma unroll
  for (int i = 0; i < 8; ++i) ones[i] = (short)0x3F80;   // bf16 1.0

  f32x4 O[4] = {};        // lane holds O[d=j2*16+hb*4+r][q=ln]
  f32x4 l_acc = {};       // all entries = l(q=ln)
  float m_run = NEGINF;   // per-lane (q=ln)
  u32* Pw = &Pbuf[w][0];

  short8 kst, vst, bc, bn;

  // ---- prologue: stage tile kt0 into buf 0; bias kt0 ----
  kst = *(const short8*)&Kt0[kt0 * 2048 + stoff];
  vst = *(const short8*)&Vt0[kt0 * 2048 + stoff];
  bc  = *(const short8*)&Bt0[kt0 * 512];
  *(short8*)&KL[0][stoff] = kst;
  *(short8*)&VL[0][stoff] = vst;
  __syncthreads();

  int cur = 0;
  for (int it = 0; it < 32; ++it) {
    const int ktn = kt0 + ((it + 1) & 31);

    // ---- issue next-tile global loads (stay in flight across barrier) ----
    kst = *(const short8*)&Kt0[ktn * 2048 + stoff];
    vst = *(const short8*)&Vt0[ktn * 2048 + stoff];
    bn  = *(const short8*)&Bt0[ktn * 512];

    // ---- swapped QK^T from LDS, accumulator init = bias ----
    // dots[j][r] = S[k = j*16 + hb*4 + r][q = ln]
    f32x4 dots[2];
#pragma unroll
    for (int j = 0; j < 2; ++j)
#pragma unroll
      for (int r = 0; r < 4; ++r)
        dots[j][r] = (float)__builtin_bit_cast(_Float16, (u16)bc[j * 4 + r]);
    __builtin_amdgcn_s_setprio(1);
#pragma unroll
    for (int kc = 0; kc < 2; ++kc)
#pragma unroll
      for (int j = 0; j < 2; ++j) {
        const short8 kfr = *(const short8*)&KL[cur][(kc * 2 + j) * 512 + l8];
        dots[j] = MFMA16(kfr, qfh[kc], dots[j]);
        dots[j] = MFMA16(kfr, qfl[kc], dots[j]);
      }
    __builtin_amdgcn_s_setprio(0);

    // ---- per-q online softmax (q=ln), defer-max THR=8 ----
    float pmax = fmaxf(fmaxf(fmaxf(dots[0][0], dots[0][1]),
                             fmaxf(dots[0][2], dots[0][3])),
                       fmaxf(fmaxf(dots[1][0], dots[1][1]),
                             fmaxf(dots[1][2], dots[1][3])));
    pmax = fmaxf(pmax, __shfl_xor(pmax, 16));
    pmax = fmaxf(pmax, __shfl_xor(pmax, 32));
    if (__any(pmax > m_run + DEFER_THR)) {
      const float mn = fmaxf(m_run, pmax);
      const float fac = exp2f(m_run - mn);     // lane-local (q=ln)
      m_run = mn;
#pragma unroll
      for (int j2 = 0; j2 < 4; ++j2) {
        O[j2][0] *= fac; O[j2][1] *= fac; O[j2][2] *= fac; O[j2][3] *= fac;
      }
      l_acc[0] *= fac; l_acc[1] *= fac; l_acc[2] *= fac; l_acc[3] *= fac;
    }
    float p[2][4];
#pragma unroll
    for (int j = 0; j < 2; ++j)
#pragma unroll
      for (int r = 0; r < 4; ++r)
        p[j][r] = exp2f(dots[j][r] - m_run);

    // ---- P-exchange via per-wave LDS (wave-synchronous) ----
#pragma unroll
    for (int j = 0; j < 2; ++j) {
      uint2 wv;
      wv.x = cvtpk(p[j][0], p[j][1]);
      wv.y = cvtpk(p[j][2], p[j][3]);
      *(uint2*)&Pw[ln * 20 + j * 8 + hb * 2] = wv;   // k = j*16+hb*4+{0..3}
    }
    const short8 pf = *(const short8*)&Pw[ln * 20 + hb * 4];  // P[k=hb*8+e][q=ln]

    // ---- swapped PV from LDS: O += V^T_A x P_B ; l += ones x P ----
    __builtin_amdgcn_s_setprio(1);
#pragma unroll
    for (int j2 = 0; j2 < 4; ++j2) {
      const short8 vfr = *(const short8*)&VL[cur][j2 * 512 + l8];
      O[j2] = MFMA16(vfr, pf, O[j2]);
    }
    l_acc = MFMA16(ones, pf, l_acc);
    __builtin_amdgcn_s_setprio(0);

    // ---- write staged tile into the other buffer; raw barrier ----
    // (vmcnt wait for kst/vst is enforced by the register dependency here;
    //  other in-flight loads are NOT drained.)
    *(short8*)&KL[cur ^ 1][stoff] = kst;
    *(short8*)&VL[cur ^ 1][stoff] = vst;
    asm volatile("s_waitcnt lgkmcnt(0)" ::: "memory");
    __builtin_amdgcn_sched_barrier(0);
    __builtin_amdgcn_s_barrier();
    __builtin_amdgcn_sched_barrier(0);
    bc = bn;
    cur ^= 1;
  }

  // ---- epilogue: write unnormalized partial O + per-q m,l ----
  const int gg = (b * H_ + h) * 128 + qt;          // [0, 2048)
  const int g  = gg * 2 + half;                    // MP/LP index
  float* Opg = (half ? Op1 : Op0) + (size_t)gg * 1024;
#pragma unroll
  for (int j2 = 0; j2 < 4; ++j2)
    *(f32x4*)&Opg[ln * 64 + j2 * 16 + hb * 4] = O[j2];
  if (hb == 0) {
    MP[g * 16 + ln] = m_run;
    LP[g * 16 + ln] = l_acc[0];
  }
}

// ---------------------------------------------------------------------------
// Kernel 3b: combine the two kv-halves, normalize, write split-bf16 attn-out.
// grid 1024 x 256; thread -> (row, 8 cols).
// ---------------------------------------------------------------------------
__global__ __launch_bounds__(256) void k_comb(
    const float* __restrict__ Op0, const float* __restrict__ Op1,
    const float* __restrict__ MP, const float* __restrict__ LP,
    u16* __restrict__ ah, u16* __restrict__ al)
{
  const int i = blockIdx.x * 256 + threadIdx.x;   // [0, 262144)
  const int row = i >> 5, cg = i & 31;
  const int c0 = cg * 8, h = c0 >> 6, d0 = c0 & 63;
  const int b = row >> 11, nn = row & 2047, qt = nn >> 4, q = nn & 15;
  const int gg = (b * H_ + h) * 128 + qt;
  const int g0 = gg * 2;

  const float m1 = MP[g0 * 16 + q],       m2 = MP[(g0 + 1) * 16 + q];
  const float l1 = LP[g0 * 16 + q],       l2 = LP[(g0 + 1) * 16 + q];
  const float mm = fmaxf(m1, m2);
  const float f1 = exp2f(m1 - mm), f2 = exp2f(m2 - mm);
  const float inv = 1.0f / (l1 * f1 + l2 * f2);

  const float* p1 = Op0 + (size_t)gg * 1024 + q * 64 + d0;
  const float* p2 = Op1 + (size_t)gg * 1024 + q * 64 + d0;
  const f32x4 a1 = *(const f32x4*)p1, b1 = *(const f32x4*)(p1 + 4);
  const f32x4 a2 = *(const f32x4*)p2, b2 = *(const f32x4*)(p2 + 4);

  u16v8 hh, ll;
#pragma unroll
  for (int e = 0; e < 4; ++e) {
    const float v = (a1[e] * f1 + a2[e] * f2) * inv;
    split2(v, &hh.v[e], &ll.v[e]);
  }
#pragma unroll
  for (int e = 0; e < 4; ++e) {
    const float v = (b1[e] * f1 + b2[e] * f2) * inv;
    split2(v, &hh.v[e + 4], &ll.v[e + 4]);
  }
  *(u16v8*)&ah[row * DIMX + c0] = hh;
  *(u16v8*)&al[row * DIMX + c0] = ll;
}

// ---------------------------------------------------------------------------
// Kernel 4: out = aout @ Wout + b_out, LDS-staged. M=8192, N=256, K=256.
// grid (4, 64): colb = bx*64; 2 M-subtiles per block; B hi+lo in 64KB LDS.
// ---------------------------------------------------------------------------
__global__ __launch_bounds__(256) void k_out(
    const u16* __restrict__ ahg, const u16* __restrict__ alg,
    const u16* __restrict__ wh, const u16* __restrict__ wl,
    const float* __restrict__ bout, float* __restrict__ out)
{
  __shared__ __align__(16) u16 BhL[64 * 256];   // 32 KB, swizzled
  __shared__ __align__(16) u16 BlL[64 * 256];   // 32 KB

  const int tid = threadIdx.x;
  const int w = tid >> 6, lane = tid & 63;
  const int ln = lane & 15, hb = lane >> 4;
  const int colb = blockIdx.x * 64;

  // ---- stage B (hi+lo) into LDS ----
  {
    short8 sb[16];
#pragma unroll
    for (int it = 0; it < 8; ++it) {
      const int c = it * 8 + (tid >> 5), k8 = tid & 31;
      sb[it]     = *(const short8*)&wh[(colb + c) * 256 + k8 * 8];
      sb[8 + it] = *(const short8*)&wl[(colb + c) * 256 + k8 * 8];
    }
#pragma unroll
    for (int it = 0; it < 8; ++it) {
      const int c = it * 8 + (tid >> 5), k8 = tid & 31;
      const int le = c * 256 + ((k8 * 8) ^ ((c & 7) << 3));
      *(short8*)&BhL[le] = sb[it];
      *(short8*)&BlL[le] = sb[8 + it];
    }
  }
  __syncthreads();

#pragma unroll
  for (int st = 0; st < 2; ++st) {
    const int mtile = blockIdx.y * 2 + st;
    const int arow = mtile * 64 + w * 16 + ln;

    short8 a_h8[8], a_l8[8];
#pragma unroll
    for (int ks = 0; ks < 8; ++ks) {
      a_h8[ks] = *(const short8*)&ahg[arow * 256 + ks * 32 + hb * 8];
      a_l8[ks] = *(const short8*)&alg[arow * 256 + ks * 32 + hb * 8];
    }

    f32x4 acc[4] = {};
#pragma unroll
    for (int ks = 0; ks < 8; ++ks) {
      const int k0 = ks * 32 + hb * 8;
#pragma unroll
      for (int j = 0; j < 4; ++j) {
        const int c = j * 16 + ln;
        const int le = c * 256 + (k0 ^ ((c & 7) << 3));
        const short8 b_h = *(const short8*)&BhL[le];
        const short8 b_l = *(const short8*)&BlL[le];
        acc[j] = MFMA16(a_h8[ks], b_h, acc[j]);
        acc[j] = MFMA16(a_l8[ks], b_h, acc[j]);
        acc[j] = MFMA16(a_h8[ks], b_l, acc[j]);
      }
    }

    const int mbase = mtile * 64 + w * 16 + hb * 4;
#pragma unroll
    for (int j = 0; j < 4; ++j) {
      const int c = colb + j * 16 + ln;
      const float bb = bout[c];
#pragma unroll
      for (int r = 0; r < 4; ++r)
        out[(mbase + r) * 256 + c] = acc[j][r] + bb;
    }
  }
}

// ---------------------------------------------------------------------------
extern "C" void kernel_launch(void* const* d_in, const int* in_sizes, int n_in,
                              void* d_out, int out_size, void* d_ws, size_t ws_size,
                              hipStream_t stream)
{
  (void)in_sizes; (void)n_in; (void)out_size; (void)ws_size;
  const float* x    = (const float*)d_in[0];
  const int*   mask = (const int*)d_in[1];
  const float* spat = (const float*)d_in[2];
  const float* wq   = (const float*)d_in[3];
  const float* wo   = (const float*)d_in[4];
  const float* bout = (const float*)d_in[5];
  float* out = (float*)d_out;

  char* ws = (char*)d_ws;
  size_t o = 0;
  auto alloc = [&](size_t bytes) -> char* {
    char* p = ws + o;
    o += (bytes + 255) & ~(size_t)255;
    return p;
  };
  u16* xh  = (u16*)alloc((size_t)M_ * 256 * 2);   // 4 MB  \ Op0 alias (8 MB)
  u16* xl  = (u16*)alloc((size_t)M_ * 256 * 2);   // 4 MB  /
  u16* wqh = (u16*)alloc((size_t)768 * 256 * 2);  // 384KB -> MP alias (256KB)
  u16* wql = (u16*)alloc((size_t)768 * 256 * 2);  // 384KB -> LP alias (256KB)
  u16* woh = (u16*)alloc((size_t)256 * 256 * 2);
  u16* wol = (u16*)alloc((size_t)256 * 256 * 2);
  u16* qh  = (u16*)alloc((size_t)16 * N_ * DH_ * 2);
  u16* ql  = (u16*)alloc((size_t)16 * N_ * DH_ * 2);
  u16* kf  = (u16*)alloc((size_t)16 * N_ * DH_ * 2);
  u16* vf  = (u16*)alloc((size_t)16 * N_ * DH_ * 2);
  u16* ah  = (u16*)alloc((size_t)M_ * 256 * 2);
  u16* al  = (u16*)alloc((size_t)M_ * 256 * 2);
  u16* biasF = (u16*)alloc((size_t)4 * 128 * 64 * 512 * 2);  // 33.5 MB fp16

  // Safe scratch aliases (sizes verified, R9-proven):
  //  Op0 (8,388,608 B) <- xh+xl (contiguous, dead after k_qkv)
  //  Op1 (8,388,608 B) <- d_out (fully overwritten by k_out)
  //  MP/LP (262,144 B) <- wqh / wql (393,216 B each, dead after k_qkv)
  float* Op0 = (float*)xh;
  float* Op1 = out;
  float* MP  = (float*)wqh;
  float* LP  = (float*)wql;

  hipLaunchKernelGGL(k_prep, dim3(7168), dim3(256), 0, stream,
                     mask, spat, x, wq, wo, biasF,
                     xh, xl, wqh, wql, woh, wol);
  hipLaunchKernelGGL(k_qkv, dim3(12, 64), dim3(256), 0, stream,
                     xh, xl, wqh, wql, qh, ql, kf, vf);
  hipLaunchKernelGGL(k_attn, dim3(1024), dim3(256), 0, stream,
                     qh, ql, kf, vf, biasF, Op0, Op1, MP, LP);
  hipLaunchKernelGGL(k_comb, dim3(1024), dim3(256), 0, stream,
                     Op0, Op1, MP, LP, ah, al);
  hipLaunchKernelGGL(k_out, dim3(4, 64), dim3(256), 0, stream,
                     ah, al, woh, wol, bout, out);
}

// Round 14
// 115.059 us; speedup vs baseline: 1.0560x; 1.0560x over previous
//
#include <hip/hip_runtime.h>

// ============================================================================
// AttentionWithSpatial: x@Wqkv -> masked/biased 4-head attention -> @Wout+b
// b=4, n=2048, dim=256, heads=4, dhead=64, scale=0.125
//
// R13 post-mortem: k_attn plateaued 54-65us across 5 structures; best was
// R12's barrier-free 54.4 (limiter: per-wave K/V global traffic + chain).
// R14: barrier-free + QBLK=32 per wave (2 q-tiles share each K/V fragment
// load -> traffic & issue per unit work halve; 2 independent softmax chains
// -> 2x in-wave ILP) + drop Q-lo in QK^T (R3 precedent: absmax unchanged).
// k_prep = R13's improved version. k_qkv/k_comb/k_out/aliases unchanged.
// ============================================================================

#define B_   4
#define N_   2048
#define H_   4
#define DH_  64
#define DIMX 256
#define M_   (B_*N_)   // 8192

#define LOG2E  1.4426950408889634f
#define NEGINF (-1e30f)
#define DEFER_THR 8.0f

typedef __attribute__((ext_vector_type(8))) short short8;
typedef __attribute__((ext_vector_type(4))) float f32x4;
typedef unsigned short u16;
typedef unsigned int   u32;

#define MFMA16(a,b,c) __builtin_amdgcn_mfma_f32_16x16x32_bf16((a),(b),(c),0,0,0)

__device__ __forceinline__ u16 f2bf(float f) {
  u32 u = __builtin_bit_cast(u32, f);
  u += 0x7fffu + ((u >> 16) & 1u);   // RNE
  return (u16)(u >> 16);
}
__device__ __forceinline__ float bf2f(u16 h) {
  u32 u = ((u32)h) << 16;
  return __builtin_bit_cast(float, u);
}
__device__ __forceinline__ void split2(float f, u16* hi, u16* lo) {
  u16 h = f2bf(f);
  *hi = h;
  *lo = f2bf(f - bf2f(h));
}
__device__ __forceinline__ u32 cvtpk(float lo, float hi) {
  u32 r;
  asm("v_cvt_pk_bf16_f32 %0, %1, %2" : "=v"(r) : "v"(lo), "v"(hi));
  return r;
}

struct u16v4 { u16 a, b, c, d; };
struct u16v8 { u16 v[8]; };

// ---------------------------------------------------------------------------
// Kernel 1 (fused prep):
//  blocks [0,4096): bias prefuse, TWO adjacent-kt records per thread
//  blocks [4096,7168): x -> xh/xl split; Wqkv/Wout transpose+split
// ---------------------------------------------------------------------------
__global__ __launch_bounds__(256) void k_prep(
    const int* __restrict__ mask, const float* __restrict__ spat,
    const float* __restrict__ x, const float* __restrict__ wq,
    const float* __restrict__ wo,
    u16* __restrict__ biasF,
    u16* __restrict__ xh, u16* __restrict__ xl,
    u16* __restrict__ wqh, u16* __restrict__ wql,
    u16* __restrict__ woh, u16* __restrict__ wol)
{
  if (blockIdx.x < 4096) {
    const int rr = blockIdx.x * 256 + threadIdx.x;    // [0, 1048576)
    const int lane = rr & 63;
    const int kt2 = (rr >> 6) & 31;                   // kt pair
    const int qt = (rr >> 11) & 127;
    const int b  = rr >> 18;
    const int kt = kt2 * 2;
    const int ln = lane & 15, hb = lane >> 4;
    const int q  = qt * 16 + ln;
    const int c0 = kt * 32 + hb * 4;
    const int base = (b * N_ + q) * N_ + c0;

    int4   m[4];
    float4 s[4];
#pragma unroll
    for (int i = 0; i < 4; ++i) {
      m[i] = *(const int4*)&mask[base + i * 16];
      s[i] = *(const float4*)&spat[base + i * 16];
    }

    const float NB = -10000.0f;
    const size_t r0 = ((size_t)((b * 128 + qt) * 64 + kt) * 64 + lane) * 8;
#pragma unroll
    for (int g = 0; g < 2; ++g) {      // record kt+g
      u16v8 o;
      const int4   ma = m[g * 2], mb = m[g * 2 + 1];
      const float4 sa = s[g * 2], sb = s[g * 2 + 1];
      o.v[0] = __builtin_bit_cast(u16, (_Float16)(ma.x ? sa.x * LOG2E : NB));
      o.v[1] = __builtin_bit_cast(u16, (_Float16)(ma.y ? sa.y * LOG2E : NB));
      o.v[2] = __builtin_bit_cast(u16, (_Float16)(ma.z ? sa.z * LOG2E : NB));
      o.v[3] = __builtin_bit_cast(u16, (_Float16)(ma.w ? sa.w * LOG2E : NB));
      o.v[4] = __builtin_bit_cast(u16, (_Float16)(mb.x ? sb.x * LOG2E : NB));
      o.v[5] = __builtin_bit_cast(u16, (_Float16)(mb.y ? sb.y * LOG2E : NB));
      o.v[6] = __builtin_bit_cast(u16, (_Float16)(mb.z ? sb.z * LOG2E : NB));
      o.v[7] = __builtin_bit_cast(u16, (_Float16)(mb.w ? sb.w * LOG2E : NB));
      *(u16v8*)&biasF[r0 + (size_t)g * 512] = o;
    }
    return;
  }

  const int NX4 = (M_ * DIMX) / 4;  // 524288
  const int NWQ = 768 * 256;        // 196608
  const int NWO = 256 * 256;        // 65536
  int i = (blockIdx.x - 4096) * 256 + threadIdx.x;
  if (i < NX4) {
    const float4 v = ((const float4*)x)[i];
    u16v4 hv, lv;
    split2(v.x, &hv.a, &lv.a);
    split2(v.y, &hv.b, &lv.b);
    split2(v.z, &hv.c, &lv.c);
    split2(v.w, &hv.d, &lv.d);
    ((u16v4*)xh)[i] = hv;
    ((u16v4*)xl)[i] = lv;
  } else if (i < NX4 + NWQ) {
    int j = i - NX4;
    int c = j >> 8, k = j & 255;            // out layout [c][k]
    split2(wq[k * 768 + c], &wqh[j], &wql[j]);
  } else if (i < NX4 + NWQ + NWO) {
    int j = i - NX4 - NWQ;
    int c = j >> 8, k = j & 255;
    split2(wo[k * 256 + c], &woh[j], &wol[j]);
  }
}

// ---------------------------------------------------------------------------
// Kernel 2: QKV GEMM, LDS-staged. M=8192, N=768, K=256. grid (12, 64).
// B tile (hi+lo) staged once in 64KB LDS, XOR-swizzled; 2 M-subtiles/block;
// 16 A loads upfront per subtile; MFMA fed from LDS.
// ---------------------------------------------------------------------------
__global__ __launch_bounds__(256) void k_qkv(
    const u16* __restrict__ xh, const u16* __restrict__ xl,
    const u16* __restrict__ wh, const u16* __restrict__ wl,
    u16* __restrict__ qh, u16* __restrict__ ql,
    u16* __restrict__ kf, u16* __restrict__ vf)
{
  __shared__ __align__(16) u16 BhL[64 * 256];   // 32 KB, swizzled
  __shared__ __align__(16) u16 BlL[64 * 256];   // 32 KB

  const int tid = threadIdx.x;
  const int w = tid >> 6, lane = tid & 63;
  const int ln = lane & 15, hb = lane >> 4;
  const int colb = blockIdx.x * 64;

  // ---- stage B (hi+lo) into LDS, reg-batched, coalesced ----
  {
    short8 sb[16];
#pragma unroll
    for (int it = 0; it < 8; ++it) {
      const int c = it * 8 + (tid >> 5), k8 = tid & 31;
      sb[it]     = *(const short8*)&wh[(colb + c) * 256 + k8 * 8];
      sb[8 + it] = *(const short8*)&wl[(colb + c) * 256 + k8 * 8];
    }
#pragma unroll
    for (int it = 0; it < 8; ++it) {
      const int c = it * 8 + (tid >> 5), k8 = tid & 31;
      const int le = c * 256 + ((k8 * 8) ^ ((c & 7) << 3));
      *(short8*)&BhL[le] = sb[it];
      *(short8*)&BlL[le] = sb[8 + it];
    }
  }
  __syncthreads();

#pragma unroll
  for (int st = 0; st < 2; ++st) {
    const int mtile = blockIdx.y * 2 + st;
    const int arow = mtile * 64 + w * 16 + ln;

    short8 a_h8[8], a_l8[8];
#pragma unroll
    for (int ks = 0; ks < 8; ++ks) {
      a_h8[ks] = *(const short8*)&xh[arow * 256 + ks * 32 + hb * 8];
      a_l8[ks] = *(const short8*)&xl[arow * 256 + ks * 32 + hb * 8];
    }

    f32x4 acc[4] = {};
#pragma unroll
    for (int ks = 0; ks < 8; ++ks) {
      const int k0 = ks * 32 + hb * 8;
#pragma unroll
      for (int j = 0; j < 4; ++j) {
        const int c = j * 16 + ln;
        const int le = c * 256 + (k0 ^ ((c & 7) << 3));
        const short8 b_h = *(const short8*)&BhL[le];
        const short8 b_l = *(const short8*)&BlL[le];
        acc[j] = MFMA16(a_h8[ks], b_h, acc[j]);
        acc[j] = MFMA16(a_l8[ks], b_h, acc[j]);
        acc[j] = MFMA16(a_h8[ks], b_l, acc[j]);
      }
    }

    const int mbase = mtile * 64 + w * 16 + hb * 4;
#pragma unroll
    for (int j = 0; j < 4; ++j) {
      const int c = colb + j * 16 + ln;
      const int which = c >> 8;        // 0=q 1=k 2=v
      const int hd = c & 255;
      const int hh = hd >> 6, d = hd & 63;
#pragma unroll
      for (int r = 0; r < 4; ++r) {
        const int m = mbase + r;
        const int bb = m >> 11, nn = m & 2047;
        const int bh = bb * H_ + hh;
        float v = acc[j][r];
        if (which == 0) {
          const int off = (bh * N_ + nn) * DH_ + d;
          v *= (0.125f * LOG2E);                 // scale + exp2-domain fold
          split2(v, &qh[off], &ql[off]);
        } else if (which == 1) {
          const int ktile = nn >> 5, jj = (nn >> 4) & 1, lnn = nn & 15;
          const int kc = d >> 5, hbb = (d >> 3) & 3, e = d & 7;
          const int off = (bh * 64 + ktile) * 2048 + (kc * 2 + jj) * 512
                        + (hbb * 16 + lnn) * 8 + e;
          kf[off] = f2bf(v);
        } else {
          const int ktile = nn >> 5, hbb = (nn >> 3) & 3, e = nn & 7;
          const int j2 = d >> 4, lnn = d & 15;
          const int off = (bh * 64 + ktile) * 2048 + j2 * 512
                        + (hbb * 16 + lnn) * 8 + e;
          vf[off] = f2bf(v);
        }
      }
    }
  }
}

// ---------------------------------------------------------------------------
// Kernel 3: flash attention partials, KV-split=2, BARRIER-FREE, QBLK=32.
// grid 512: bid -> half=bid&1, bh=(bid>>1)&15, qp=bid>>5 in [0,16).
// Wave w handles q-tiles qp*8 + w*2 + {0,1} (32 q-rows) -- each K/V
// fragment load is used by BOTH q-tiles (traffic per unit work halved);
// the two softmax chains are independent (2x in-wave ILP).
// Q hi-only in QK^T (R3 precedent: split-term drop, error << threshold).
// K reg-dbuf one tile ahead; V issue-early/use-late; bias fp16 acc-init.
// Swapped PV: O[d][q], q=ln lane-local rescale/l. No __syncthreads.
// ---------------------------------------------------------------------------
__global__ __launch_bounds__(256) void k_attn(
    const u16* __restrict__ qhg,
    const u16* __restrict__ kfg, const u16* __restrict__ vfg,
    const u16* __restrict__ biasF,
    float* __restrict__ Op0, float* __restrict__ Op1,
    float* __restrict__ MP, float* __restrict__ LP)
{
  __shared__ __align__(16) u32 Pbuf[4][2][320];   // 10 KB: per-wave, per-qi

  const int bid = blockIdx.x;
  const int half = bid & 1;
  const int bh = (bid >> 1) & 15;
  const int qp = bid >> 5;                     // [0,16)
  const int b = bh >> 2, h = bh & 3;
  const int kt0 = half * 32;

  const int tid = threadIdx.x;
  const int w = tid >> 6, lane = tid & 63;
  const int qt0 = qp * 8 + w * 2;              // q-tiles qt0, qt0+1
  const int ln = lane & 15, hb = lane >> 4;

  // ---- Q hi fragments (pre-scaled by 0.125*log2e), per q-tile ----
  short8 qf[2][2];
#pragma unroll
  for (int qi = 0; qi < 2; ++qi) {
    const int base = ((b * H_ + h) * N_ + (qt0 + qi) * 16 + ln) * DH_;
    qf[qi][0] = *(const short8*)&qhg[base + hb * 8];
    qf[qi][1] = *(const short8*)&qhg[base + 32 + hb * 8];
  }

  // per-lane fragment bases (lane*8 folded; per-tile offset = kt*2048)
  const u16* Kt0 = kfg + (size_t)((b * H_ + h) * 64) * 2048 + lane * 8;
  const u16* Vt0 = vfg + (size_t)((b * H_ + h) * 64) * 2048 + lane * 8;
  const u16* Bt0 = biasF + (size_t)((b * 128 + qt0) * 64) * 512 + lane * 8;
  const u16* Bt1 = Bt0 + (size_t)64 * 512;     // q-tile qt0+1

  short8 ones;
#pragma unroll
  for (int i = 0; i < 8; ++i) ones[i] = (short)0x3F80;   // bf16 1.0

  f32x4 O[2][4] = {};      // lane holds O[qi][d=j2*16+hb*4+r][q=ln]
  f32x4 l_acc[2] = {};     // all entries = l(q=ln)
  float m_run[2] = {NEGINF, NEGINF};

  short8 Ka[4], Kb[4];
  short8 bc[2], bn[2];

  // ---- prologue: K tile kt0 + bias kt0 ----
#pragma unroll
  for (int i = 0; i < 4; ++i)
    Ka[i] = *(const short8*)&Kt0[kt0 * 2048 + i * 512];
  bc[0] = *(const short8*)&Bt0[kt0 * 512];
  bc[1] = *(const short8*)&Bt1[kt0 * 512];

  auto body = [&](short8 (&Kc)[4], short8 (&Kn)[4],
                  short8 (&bcur)[2], short8 (&bnxt)[2], int ktc, int ktn) {
    // ---- issue loads: V for THIS tile (used late), K+bias for NEXT ----
    short8 Vc[4];
#pragma unroll
    for (int i = 0; i < 4; ++i)
      Vc[i] = *(const short8*)&Vt0[ktc * 2048 + i * 512];
#pragma unroll
    for (int i = 0; i < 4; ++i)
      Kn[i] = *(const short8*)&Kt0[ktn * 2048 + i * 512];
    bnxt[0] = *(const short8*)&Bt0[ktn * 512];
    bnxt[1] = *(const short8*)&Bt1[ktn * 512];

#pragma unroll
    for (int qi = 0; qi < 2; ++qi) {
      // ---- swapped QK^T (Q hi only), accumulator init = bias ----
      // dots[j][r] = S[k = j*16 + hb*4 + r][q = ln]
      f32x4 dots[2];
#pragma unroll
      for (int j = 0; j < 2; ++j)
#pragma unroll
        for (int r = 0; r < 4; ++r)
          dots[j][r] =
              (float)__builtin_bit_cast(_Float16, (u16)bcur[qi][j * 4 + r]);
      __builtin_amdgcn_s_setprio(1);
#pragma unroll
      for (int kc = 0; kc < 2; ++kc)
#pragma unroll
        for (int j = 0; j < 2; ++j)
          dots[j] = MFMA16(Kc[kc * 2 + j], qf[qi][kc], dots[j]);
      __builtin_amdgcn_s_setprio(0);

      // ---- per-q online softmax (q=ln), defer-max THR=8 ----
      float pmax = fmaxf(fmaxf(fmaxf(dots[0][0], dots[0][1]),
                               fmaxf(dots[0][2], dots[0][3])),
                         fmaxf(fmaxf(dots[1][0], dots[1][1]),
                               fmaxf(dots[1][2], dots[1][3])));
      pmax = fmaxf(pmax, __shfl_xor(pmax, 16));
      pmax = fmaxf(pmax, __shfl_xor(pmax, 32));
      if (__any(pmax > m_run[qi] + DEFER_THR)) {
        const float mn = fmaxf(m_run[qi], pmax);
        const float fac = exp2f(m_run[qi] - mn);   // lane-local (q=ln)
        m_run[qi] = mn;
#pragma unroll
        for (int j2 = 0; j2 < 4; ++j2) {
          O[qi][j2][0] *= fac; O[qi][j2][1] *= fac;
          O[qi][j2][2] *= fac; O[qi][j2][3] *= fac;
        }
        l_acc[qi][0] *= fac; l_acc[qi][1] *= fac;
        l_acc[qi][2] *= fac; l_acc[qi][3] *= fac;
      }
      float p[2][4];
#pragma unroll
      for (int j = 0; j < 2; ++j)
#pragma unroll
        for (int r = 0; r < 4; ++r)
          p[j][r] = exp2f(dots[j][r] - m_run[qi]);

      // ---- P-exchange via per-wave LDS (wave-synchronous) ----
      u32* Pw = &Pbuf[w][qi][0];
#pragma unroll
      for (int j = 0; j < 2; ++j) {
        uint2 wv;
        wv.x = cvtpk(p[j][0], p[j][1]);
        wv.y = cvtpk(p[j][2], p[j][3]);
        *(uint2*)&Pw[ln * 20 + j * 8 + hb * 2] = wv;  // k = j*16+hb*4+{0..3}
      }
      const short8 pf = *(const short8*)&Pw[ln * 20 + hb * 4];

      // ---- swapped PV: O += V^T_A x P_B ; l += ones x P ----
      __builtin_amdgcn_s_setprio(1);
#pragma unroll
      for (int j2 = 0; j2 < 4; ++j2)
        O[qi][j2] = MFMA16(Vc[j2], pf, O[qi][j2]);
      l_acc[qi] = MFMA16(ones, pf, l_acc[qi]);
      __builtin_amdgcn_s_setprio(0);
    }
  };

  for (int it = 0; it < 16; ++it) {
    const int t  = kt0 + 2 * it;
    const int t2 = kt0 + ((2 * it + 2) & 31);  // wraps on last prefetch
    body(Ka, Kb, bc, bn, t,     t + 1);
    body(Kb, Ka, bn, bc, t + 1, t2);
  }

  // ---- epilogue: write unnormalized partial O + per-q m,l ----
#pragma unroll
  for (int qi = 0; qi < 2; ++qi) {
    const int gg = (b * H_ + h) * 128 + qt0 + qi;    // [0, 2048)
    const int g  = gg * 2 + half;                    // MP/LP index
    float* Opg = (half ? Op1 : Op0) + (size_t)gg * 1024;
#pragma unroll
    for (int j2 = 0; j2 < 4; ++j2)
      *(f32x4*)&Opg[ln * 64 + j2 * 16 + hb * 4] = O[qi][j2];
    if (hb == 0) {
      MP[g * 16 + ln] = m_run[qi];
      LP[g * 16 + ln] = l_acc[qi][0];
    }
  }
}

// ---------------------------------------------------------------------------
// Kernel 3b: combine the two kv-halves, normalize, write split-bf16 attn-out.
// grid 1024 x 256; thread -> (row, 8 cols).
// ---------------------------------------------------------------------------
__global__ __launch_bounds__(256) void k_comb(
    const float* __restrict__ Op0, const float* __restrict__ Op1,
    const float* __restrict__ MP, const float* __restrict__ LP,
    u16* __restrict__ ah, u16* __restrict__ al)
{
  const int i = blockIdx.x * 256 + threadIdx.x;   // [0, 262144)
  const int row = i >> 5, cg = i & 31;
  const int c0 = cg * 8, h = c0 >> 6, d0 = c0 & 63;
  const int b = row >> 11, nn = row & 2047, qt = nn >> 4, q = nn & 15;
  const int gg = (b * H_ + h) * 128 + qt;
  const int g0 = gg * 2;

  const float m1 = MP[g0 * 16 + q],       m2 = MP[(g0 + 1) * 16 + q];
  const float l1 = LP[g0 * 16 + q],       l2 = LP[(g0 + 1) * 16 + q];
  const float mm = fmaxf(m1, m2);
  const float f1 = exp2f(m1 - mm), f2 = exp2f(m2 - mm);
  const float inv = 1.0f / (l1 * f1 + l2 * f2);

  const float* p1 = Op0 + (size_t)gg * 1024 + q * 64 + d0;
  const float* p2 = Op1 + (size_t)gg * 1024 + q * 64 + d0;
  const f32x4 a1 = *(const f32x4*)p1, b1 = *(const f32x4*)(p1 + 4);
  const f32x4 a2 = *(const f32x4*)p2, b2 = *(const f32x4*)(p2 + 4);

  u16v8 hh, ll;
#pragma unroll
  for (int e = 0; e < 4; ++e) {
    const float v = (a1[e] * f1 + a2[e] * f2) * inv;
    split2(v, &hh.v[e], &ll.v[e]);
  }
#pragma unroll
  for (int e = 0; e < 4; ++e) {
    const float v = (b1[e] * f1 + b2[e] * f2) * inv;
    split2(v, &hh.v[e + 4], &ll.v[e + 4]);
  }
  *(u16v8*)&ah[row * DIMX + c0] = hh;
  *(u16v8*)&al[row * DIMX + c0] = ll;
}

// ---------------------------------------------------------------------------
// Kernel 4: out = aout @ Wout + b_out, LDS-staged. M=8192, N=256, K=256.
// grid (4, 64): colb = bx*64; 2 M-subtiles per block; B hi+lo in 64KB LDS.
// ---------------------------------------------------------------------------
__global__ __launch_bounds__(256) void k_out(
    const u16* __restrict__ ahg, const u16* __restrict__ alg,
    const u16* __restrict__ wh, const u16* __restrict__ wl,
    const float* __restrict__ bout, float* __restrict__ out)
{
  __shared__ __align__(16) u16 BhL[64 * 256];   // 32 KB, swizzled
  __shared__ __align__(16) u16 BlL[64 * 256];   // 32 KB

  const int tid = threadIdx.x;
  const int w = tid >> 6, lane = tid & 63;
  const int ln = lane & 15, hb = lane >> 4;
  const int colb = blockIdx.x * 64;

  // ---- stage B (hi+lo) into LDS ----
  {
    short8 sb[16];
#pragma unroll
    for (int it = 0; it < 8; ++it) {
      const int c = it * 8 + (tid >> 5), k8 = tid & 31;
      sb[it]     = *(const short8*)&wh[(colb + c) * 256 + k8 * 8];
      sb[8 + it] = *(const short8*)&wl[(colb + c) * 256 + k8 * 8];
    }
#pragma unroll
    for (int it = 0; it < 8; ++it) {
      const int c = it * 8 + (tid >> 5), k8 = tid & 31;
      const int le = c * 256 + ((k8 * 8) ^ ((c & 7) << 3));
      *(short8*)&BhL[le] = sb[it];
      *(short8*)&BlL[le] = sb[8 + it];
    }
  }
  __syncthreads();

#pragma unroll
  for (int st = 0; st < 2; ++st) {
    const int mtile = blockIdx.y * 2 + st;
    const int arow = mtile * 64 + w * 16 + ln;

    short8 a_h8[8], a_l8[8];
#pragma unroll
    for (int ks = 0; ks < 8; ++ks) {
      a_h8[ks] = *(const short8*)&ahg[arow * 256 + ks * 32 + hb * 8];
      a_l8[ks] = *(const short8*)&alg[arow * 256 + ks * 32 + hb * 8];
    }

    f32x4 acc[4] = {};
#pragma unroll
    for (int ks = 0; ks < 8; ++ks) {
      const int k0 = ks * 32 + hb * 8;
#pragma unroll
      for (int j = 0; j < 4; ++j) {
        const int c = j * 16 + ln;
        const int le = c * 256 + (k0 ^ ((c & 7) << 3));
        const short8 b_h = *(const short8*)&BhL[le];
        const short8 b_l = *(const short8*)&BlL[le];
        acc[j] = MFMA16(a_h8[ks], b_h, acc[j]);
        acc[j] = MFMA16(a_l8[ks], b_h, acc[j]);
        acc[j] = MFMA16(a_h8[ks], b_l, acc[j]);
      }
    }

    const int mbase = mtile * 64 + w * 16 + hb * 4;
#pragma unroll
    for (int j = 0; j < 4; ++j) {
      const int c = colb + j * 16 + ln;
      const float bb = bout[c];
#pragma unroll
      for (int r = 0; r < 4; ++r)
        out[(mbase + r) * 256 + c] = acc[j][r] + bb;
    }
  }
}

// ---------------------------------------------------------------------------
extern "C" void kernel_launch(void* const* d_in, const int* in_sizes, int n_in,
                              void* d_out, int out_size, void* d_ws, size_t ws_size,
                              hipStream_t stream)
{
  (void)in_sizes; (void)n_in; (void)out_size; (void)ws_size;
  const float* x    = (const float*)d_in[0];
  const int*   mask = (const int*)d_in[1];
  const float* spat = (const float*)d_in[2];
  const float* wq   = (const float*)d_in[3];
  const float* wo   = (const float*)d_in[4];
  const float* bout = (const float*)d_in[5];
  float* out = (float*)d_out;

  char* ws = (char*)d_ws;
  size_t o = 0;
  auto alloc = [&](size_t bytes) -> char* {
    char* p = ws + o;
    o += (bytes + 255) & ~(size_t)255;
    return p;
  };
  u16* xh  = (u16*)alloc((size_t)M_ * 256 * 2);   // 4 MB  \ Op0 alias (8 MB)
  u16* xl  = (u16*)alloc((size_t)M_ * 256 * 2);   // 4 MB  /
  u16* wqh = (u16*)alloc((size_t)768 * 256 * 2);  // 384KB -> MP alias (256KB)
  u16* wql = (u16*)alloc((size_t)768 * 256 * 2);  // 384KB -> LP alias (256KB)
  u16* woh = (u16*)alloc((size_t)256 * 256 * 2);
  u16* wol = (u16*)alloc((size_t)256 * 256 * 2);
  u16* qh  = (u16*)alloc((size_t)16 * N_ * DH_ * 2);
  u16* ql  = (u16*)alloc((size_t)16 * N_ * DH_ * 2);
  u16* kf  = (u16*)alloc((size_t)16 * N_ * DH_ * 2);
  u16* vf  = (u16*)alloc((size_t)16 * N_ * DH_ * 2);
  u16* ah  = (u16*)alloc((size_t)M_ * 256 * 2);
  u16* al  = (u16*)alloc((size_t)M_ * 256 * 2);
  u16* biasF = (u16*)alloc((size_t)4 * 128 * 64 * 512 * 2);  // 33.5 MB fp16

  // Safe scratch aliases (sizes verified, R9-proven):
  //  Op0 (8,388,608 B) <- xh+xl (contiguous, dead after k_qkv)
  //  Op1 (8,388,608 B) <- d_out (fully overwritten by k_out)
  //  MP/LP (262,144 B) <- wqh / wql (393,216 B each, dead after k_qkv)
  float* Op0 = (float*)xh;
  float* Op1 = out;
  float* MP  = (float*)wqh;
  float* LP  = (float*)wql;

  hipLaunchKernelGGL(k_prep, dim3(7168), dim3(256), 0, stream,
                     mask, spat, x, wq, wo, biasF,
                     xh, xl, wqh, wql, woh, wol);
  hipLaunchKernelGGL(k_qkv, dim3(12, 64), dim3(256), 0, stream,
                     xh, xl, wqh, wql, qh, ql, kf, vf);
  hipLaunchKernelGGL(k_attn, dim3(512), dim3(256), 0, stream,
                     qh, kf, vf, biasF, Op0, Op1, MP, LP);
  hipLaunchKernelGGL(k_comb, dim3(1024), dim3(256), 0, stream,
                     Op0, Op1, MP, LP, ah, al);
  hipLaunchKernelGGL(k_out, dim3(4, 64), dim3(256), 0, stream,
                     ah, al, woh, wol, bout, out);
}